// Round 4
// baseline (897.112 us; speedup 1.0000x reference)
//
#include <hip/hip_runtime.h>
#include <hip/hip_cooperative_groups.h>
#include <math.h>

namespace cg = cooperative_groups;

#define NUM_HOP 3
#define VOCAB   32000
#define DIM     512
#define MEM     60
#define BS      64
#define STORY   50
#define SENT    32
#define QLEN    16

#define SZ      ((size_t)BS * STORY * DIM)
#define TBL     ((size_t)VOCAB * DIM)
#define NBLK    512
#define NTHR    256
#define NSENT   (4 * BS * STORY)          // 12800 sentence tasks
#define NTASK   (NSENT + BS)              // + 64 query tasks

typedef short v8s __attribute__((ext_vector_type(8)));   // 8 bf16
typedef float v4f __attribute__((ext_vector_type(4)));

static __device__ __forceinline__ ushort f2bf(float x) {
    union { float f; unsigned u; } v; v.f = x;
    unsigned r = (v.u + 0x7FFFu + ((v.u >> 16) & 1u)) >> 16;
    return (ushort)r;
}

union __align__(16) SMem {
    struct { float su[DIM]; float sw[64]; float up[4][DIM]; } hop;   // 10.3 KB
    struct { ushort a[64 * 128]; ushort u[64 * 128]; } log;          // 32 KB
    struct { float red[8]; } r;
};

__global__ __launch_bounds__(NTHR, 2)
void k_fused(const float* __restrict__ A,
             const int*   __restrict__ ctx,
             const int*   __restrict__ query,
             const float* __restrict__ T_A,
             float*       __restrict__ mw,
             float*       __restrict__ c,
             float*       __restrict__ u,
             ushort*      __restrict__ ubf,
             ushort*      __restrict__ a3bf,
             float*       __restrict__ pairs,
             float*       __restrict__ out) {
    cg::grid_group grid = cg::this_grid();
    __shared__ SMem sm;
    const int tid = threadIdx.x;
    const int blk = blockIdx.x;

    // ============ Phase A: gather (all tables) + query encode ============
    {
        const int hb = blk * 2 + (tid >> 7);   // half-block 0..1023
        const int lt = tid & 127;
        const int d  = lt * 4;
        const float invD = 1.0f / (float)DIM;
        for (int t = hb; t < NTASK; t += 2 * NBLK) {
            if (t < NSENT) {
                const int pass = t / (BS * STORY);
                const int bs   = t - pass * (BS * STORY);
                const float* table = A + (size_t)pass * TBL;
                const int*   cw    = ctx + bs * SENT;
                float4 m  = make_float4(0.f, 0.f, 0.f, 0.f);
                float4 cc = make_float4(0.f, 0.f, 0.f, 0.f);
                #pragma unroll 8
                for (int w = 0; w < SENT; ++w) {
                    const int idx = cw[w];
                    if (idx == 0) continue;
                    const float4 a = *(const float4*)(table + (size_t)idx * DIM + d);
                    const float aw = 1.0f - (float)(w + 1) * (1.0f / (float)SENT);
                    const float bw = 1.0f - (float)(2 * (w + 1)) * (1.0f / (float)SENT);
                    m.x = fmaf(a.x, aw - bw * (float)(d + 1) * invD, m.x);
                    m.y = fmaf(a.y, aw - bw * (float)(d + 2) * invD, m.y);
                    m.z = fmaf(a.z, aw - bw * (float)(d + 3) * invD, m.z);
                    m.w = fmaf(a.w, aw - bw * (float)(d + 4) * invD, m.w);
                    cc.x += a.x; cc.y += a.y; cc.z += a.z; cc.w += a.w;
                }
                if (pass < 3)
                    *(float4*)(mw + (size_t)pass * SZ + (size_t)bs * DIM + d) = m;
                if (pass > 0)
                    *(float4*)(c + (size_t)(pass - 1) * SZ + (size_t)bs * DIM + d) = cc;
            } else {
                const int b = t - NSENT;
                const int* q = query + b * QLEN;
                float4 acc = make_float4(0.f, 0.f, 0.f, 0.f);
                for (int tt = 0; tt < QLEN; ++tt) {
                    const int idx = q[tt];
                    if (idx != 0) {
                        const float4 a = *(const float4*)(A + (size_t)idx * DIM + d);
                        acc.x += a.x; acc.y += a.y; acc.z += a.z; acc.w += a.w;
                    }
                }
                *(float4*)(u + (size_t)b * DIM + d) = acc;
            }
        }
    }
    grid.sync();   // B

    // ===== Phase C: hops (blocks 0..63) | A3 -> bf16 convert (64..511) =====
    if (blk < BS) {
        const int b    = blk;
        const int wave = tid >> 6;
        const int lane = tid & 63;
        sm.hop.su[tid]       = u[(size_t)b * DIM + tid];
        sm.hop.su[tid + 256] = u[(size_t)b * DIM + tid + 256];
        __syncthreads();
        for (int h = 0; h < NUM_HOP; ++h) {
            const float* mwh = mw + (size_t)h * SZ + (size_t)b * STORY * DIM;
            const float* ch  = c  + (size_t)h * SZ + (size_t)b * STORY * DIM;
            const float4 u0 = *(const float4*)(&sm.hop.su[lane * 8]);
            const float4 u1 = *(const float4*)(&sm.hop.su[lane * 8 + 4]);
            for (int s = wave; s < STORY; s += 4) {
                const float* mrow = mwh + (size_t)s * DIM + lane * 8;
                const float* trow = T_A + (size_t)s * DIM + lane * 8;
                const float4 m0 = *(const float4*)(mrow);
                const float4 m1 = *(const float4*)(mrow + 4);
                const float4 t0 = *(const float4*)(trow);
                const float4 t1 = *(const float4*)(trow + 4);
                float p = (m0.x + t0.x) * u0.x + (m0.y + t0.y) * u0.y +
                          (m0.z + t0.z) * u0.z + (m0.w + t0.w) * u0.w +
                          (m1.x + t1.x) * u1.x + (m1.y + t1.y) * u1.y +
                          (m1.z + t1.z) * u1.z + (m1.w + t1.w) * u1.w;
                for (int off = 32; off; off >>= 1) p += __shfl_down(p, off);
                if (lane == 0) sm.hop.sw[s] = p;
            }
            __syncthreads();
            if (tid < 64) {
                const float v = (tid < STORY) ? sm.hop.sw[tid] : -1e30f;
                float mx = v;
                for (int off = 32; off; off >>= 1) mx = fmaxf(mx, __shfl_down(mx, off));
                mx = __shfl(mx, 0);
                const float e = (tid < STORY) ? __expf(v - mx) : 0.f;
                float smm = e;
                for (int off = 32; off; off >>= 1) smm += __shfl_down(smm, off);
                smm = __shfl(smm, 0);
                if (tid < STORY) sm.hop.sw[tid] = e / smm;
            }
            __syncthreads();
            float4 a0 = make_float4(0.f, 0.f, 0.f, 0.f);
            float4 a1 = make_float4(0.f, 0.f, 0.f, 0.f);
            for (int s = wave; s < STORY; s += 4) {
                const float  w    = sm.hop.sw[s];
                const float* crow = ch + (size_t)s * DIM + lane * 8;
                const float4 c0 = *(const float4*)(crow);
                const float4 c1 = *(const float4*)(crow + 4);
                a0.x = fmaf(w, c0.x, a0.x); a0.y = fmaf(w, c0.y, a0.y);
                a0.z = fmaf(w, c0.z, a0.z); a0.w = fmaf(w, c0.w, a0.w);
                a1.x = fmaf(w, c1.x, a1.x); a1.y = fmaf(w, c1.y, a1.y);
                a1.z = fmaf(w, c1.z, a1.z); a1.w = fmaf(w, c1.w, a1.w);
            }
            *(float4*)(&sm.hop.up[wave][lane * 8])     = a0;
            *(float4*)(&sm.hop.up[wave][lane * 8 + 4]) = a1;
            __syncthreads();
            sm.hop.su[tid] += sm.hop.up[0][tid] + sm.hop.up[1][tid] +
                              sm.hop.up[2][tid] + sm.hop.up[3][tid];
            sm.hop.su[tid + 256] += sm.hop.up[0][tid + 256] + sm.hop.up[1][tid + 256] +
                                    sm.hop.up[2][tid + 256] + sm.hop.up[3][tid + 256];
            __syncthreads();
        }
        ubf[(size_t)b * DIM + tid]       = f2bf(sm.hop.su[tid]);
        ubf[(size_t)b * DIM + tid + 256] = f2bf(sm.hop.su[tid + 256]);
    } else {
        // convert A3 fp32 -> bf16 into ws (reads are L3-warm from gather pass 3)
        const float* A3 = A + 3 * TBL;
        const size_t n8 = TBL / 8;                       // 2,048,000 chunks
        for (size_t i = (size_t)(blk - BS) * NTHR + tid; i < n8;
             i += (size_t)(NBLK - BS) * NTHR) {
            const float* src = A3 + i * 8;
            const float4 f0 = *(const float4*)(src);
            const float4 f1 = *(const float4*)(src + 4);
            union { ushort h[8]; uint4 q; } pk;
            pk.h[0] = f2bf(f0.x); pk.h[1] = f2bf(f0.y);
            pk.h[2] = f2bf(f0.z); pk.h[3] = f2bf(f0.w);
            pk.h[4] = f2bf(f1.x); pk.h[5] = f2bf(f1.y);
            pk.h[6] = f2bf(f1.z); pk.h[7] = f2bf(f1.w);
            *(uint4*)(a3bf + i * 8) = pk.q;
        }
    }
    grid.sync();   // D

    // ============ Phase E: logits = u @ A3^T via bf16 MFMA ============
    if (blk < VOCAB / 64) {
        const int lane = tid & 63;
        const int wave = tid >> 6;
        const int i16  = lane & 15;
        const int quad = lane >> 4;
        const int row0 = blk * 64;
        v4f acc[4];
        #pragma unroll
        for (int nt = 0; nt < 4; ++nt) acc[nt] = (v4f){0.f, 0.f, 0.f, 0.f};
        for (int ko = 0; ko < 4; ++ko) {
            __syncthreads();
            #pragma unroll
            for (int it = 0; it < 4; ++it) {
                const int i = it * 256 + tid;
                const int r = i >> 4, g = i & 15;
                const uint4 v = *(const uint4*)(a3bf + (size_t)(row0 + r) * DIM + ko * 128 + g * 8);
                *(uint4*)(&sm.log.a[r * 128 + ((g ^ (r & 7)) * 8)]) = v;
            }
            #pragma unroll
            for (int it = 0; it < 4; ++it) {
                const int i = it * 256 + tid;
                const int n = i >> 4, g = i & 15;
                const uint4 v = *(const uint4*)(ubf + (size_t)n * DIM + ko * 128 + g * 8);
                *(uint4*)(&sm.log.u[n * 128 + ((g ^ (n & 7)) * 8)]) = v;
            }
            __syncthreads();
            const int arow = wave * 16 + i16;
            #pragma unroll
            for (int ki = 0; ki < 4; ++ki) {
                const int ga = ki * 4 + quad;
                const v8s a = *(const v8s*)(&sm.log.a[arow * 128 + ((ga ^ (arow & 7)) * 8)]);
                #pragma unroll
                for (int nt = 0; nt < 4; ++nt) {
                    const int n = nt * 16 + i16;
                    const v8s bb = *(const v8s*)(&sm.log.u[n * 128 + ((ga ^ (n & 7)) * 8)]);
                    acc[nt] = __builtin_amdgcn_mfma_f32_16x16x32_bf16(a, bb, acc[nt], 0, 0, 0);
                }
            }
        }
        const int vbase = row0 + wave * 16 + quad * 4;
        #pragma unroll
        for (int nt = 0; nt < 4; ++nt) {
            const int bcol = nt * 16 + i16;
            #pragma unroll
            for (int r = 0; r < 4; ++r)
                out[(size_t)bcol * VOCAB + vbase + r] = acc[nt][r];
        }
    }
    grid.sync();   // F

    // ============ Phase G: vsm partial max/sum (b = blk/8, seg = blk%8) ====
    const int vb  = blk >> 3;
    const int seg = blk & 7;
    float* row = out + (size_t)vb * VOCAB + seg * 4000;
    float x[16];
    #pragma unroll
    for (int k = 0; k < 15; ++k) x[k] = row[tid + k * 256];
    const bool extra = (tid < 4000 - 15 * 256);
    x[15] = extra ? row[tid + 15 * 256] : -1e30f;

    float mx = -1e30f;
    #pragma unroll
    for (int k = 0; k < 16; ++k) mx = fmaxf(mx, x[k]);
    for (int off = 32; off; off >>= 1) mx = fmaxf(mx, __shfl_down(mx, off));
    if ((tid & 63) == 0) sm.r.red[tid >> 6] = mx;
    __syncthreads();
    mx = fmaxf(fmaxf(sm.r.red[0], sm.r.red[1]), fmaxf(sm.r.red[2], sm.r.red[3]));
    __syncthreads();
    float sum = 0.f;
    #pragma unroll
    for (int k = 0; k < 16; ++k) { x[k] = __expf(x[k] - mx); sum += x[k]; }
    for (int off = 32; off; off >>= 1) sum += __shfl_down(sum, off);
    if ((tid & 63) == 0) sm.r.red[4 + (tid >> 6)] = sum;
    __syncthreads();
    sum = sm.r.red[4] + sm.r.red[5] + sm.r.red[6] + sm.r.red[7];
    if (tid == 0) { pairs[blk * 2] = mx; pairs[blk * 2 + 1] = sum; }
    grid.sync();   // H

    // ============ Phase I: combine + normalize (cached x[] survive) ========
    float M = -1e30f;
    #pragma unroll
    for (int j = 0; j < 8; ++j) M = fmaxf(M, pairs[(vb * 8 + j) * 2]);
    float S = 0.f;
    #pragma unroll
    for (int j = 0; j < 8; ++j)
        S += pairs[(vb * 8 + j) * 2 + 1] * __expf(pairs[(vb * 8 + j) * 2] - M);
    const float scale = __expf(mx - M) / S;
    #pragma unroll
    for (int k = 0; k < 15; ++k) row[tid + k * 256] = x[k] * scale;
    if (extra) row[tid + 15 * 256] = x[15] * scale;
}

// ---------------------------------------------------------------------------
extern "C" void kernel_launch(void* const* d_in, const int* in_sizes, int n_in,
                              void* d_out, int out_size, void* d_ws, size_t ws_size,
                              hipStream_t stream) {
    const int*   ctx   = (const int*)d_in[0];
    const int*   query = (const int*)d_in[1];
    const float* A     = (const float*)d_in[2];
    const float* T_A   = (const float*)d_in[3];
    float* out = (float*)d_out;

    float*  u     = (float*)d_ws;                         // BS*DIM f
    float*  pairs = u + (size_t)BS * DIM;                 // 1024 f
    ushort* ubf   = (ushort*)(pairs + 1024);              // BS*DIM bf16
    ushort* a3bf  = ubf + (size_t)BS * DIM;               // TBL bf16
    float*  mw    = (float*)(a3bf + TBL);                 // 3*SZ f
    float*  c     = mw + 3 * SZ;                          // 3*SZ f

    void* args[] = {(void*)&A, (void*)&ctx, (void*)&query, (void*)&T_A,
                    (void*)&mw, (void*)&c, (void*)&u, (void*)&ubf,
                    (void*)&a3bf, (void*)&pairs, (void*)&out};
    hipLaunchCooperativeKernel((void*)k_fused, dim3(NBLK), dim3(NTHR),
                               args, 0, stream);
}

// Round 5
// 663.409 us; speedup vs baseline: 1.3523x; 1.3523x over previous
//
#include <hip/hip_runtime.h>
#include <hip/hip_cooperative_groups.h>
#include <math.h>

namespace cg = cooperative_groups;

#define NUM_HOP 3
#define VOCAB   32000
#define DIM     512
#define MEM     60
#define BS      64
#define STORY   50
#define SENT    32
#define QLEN    16

#define SZ      ((size_t)BS * STORY * DIM)
#define TBL     ((size_t)VOCAB * DIM)
#define NSENT   (4 * BS * STORY)          // 12800 sentence tasks
#define TBLK    512                       // tail co-op grid
#define NTHR    256

typedef short v8s __attribute__((ext_vector_type(8)));   // 8 bf16
typedef float v4f __attribute__((ext_vector_type(4)));

static __device__ __forceinline__ ushort f2bf(float x) {
    union { float f; unsigned u; } v; v.f = x;
    unsigned r = (v.u + 0x7FFFu + ((v.u >> 16) & 1u)) >> 16;
    return (ushort)r;
}

// ---------------------------------------------------------------------------
// Gather, branchless. Blocks [0, NSENT): pass p = blk/3200 over table A[p].
//   c'[bs]  = sum_w z*A[p][ctx]          (z = idx!=0; row-0 masking)
//   S2[bs]  = sum_w z*bw(w)*A[p][ctx],   bw = 1 - (w+1)/16
//   mw[bs,k] = 0.5*(c'+S2) - (k/512)*S2  (pe identity: aw = (1+bw)/2)
// Blocks [NSENT, +BS): u[b] = sum_t z*A[0][query[b,t]]
__global__ __launch_bounds__(128) void k_gather(const float* __restrict__ A,
                                                const int*   __restrict__ ctx,
                                                const int*   __restrict__ query,
                                                float*       __restrict__ mw,
                                                float*       __restrict__ c,
                                                float*       __restrict__ u) {
    const int blk = blockIdx.x;
    const int d   = threadIdx.x * 4;
    if (blk >= NSENT) {
        const int b = blk - NSENT;
        const int* q = query + b * QLEN;
        float4 acc = make_float4(0.f, 0.f, 0.f, 0.f);
        #pragma unroll 8
        for (int t = 0; t < QLEN; ++t) {
            const int idx = q[t];
            const float z = (idx != 0) ? 1.f : 0.f;
            const float4 a = *(const float4*)(A + (size_t)idx * DIM + d);
            acc.x = fmaf(z, a.x, acc.x); acc.y = fmaf(z, a.y, acc.y);
            acc.z = fmaf(z, a.z, acc.z); acc.w = fmaf(z, a.w, acc.w);
        }
        *(float4*)(u + (size_t)b * DIM + d) = acc;
        return;
    }
    const int pass = blk / (BS * STORY);
    const int bs   = blk - pass * (BS * STORY);
    const float* table = A + (size_t)pass * TBL;
    const int*   cw    = ctx + bs * SENT;

    float4 cc = make_float4(0.f, 0.f, 0.f, 0.f);
    float4 s2 = make_float4(0.f, 0.f, 0.f, 0.f);
    #pragma unroll 8
    for (int w = 0; w < SENT; ++w) {
        const int idx = cw[w];                       // wave-uniform scalar
        const float4 a = *(const float4*)(table + (size_t)idx * DIM + d);
        const float z  = (idx != 0) ? 1.f : 0.f;
        const float zb = z * (1.f - (float)(w + 1) * (1.f / 16.f));
        cc.x = fmaf(z,  a.x, cc.x); cc.y = fmaf(z,  a.y, cc.y);
        cc.z = fmaf(z,  a.z, cc.z); cc.w = fmaf(z,  a.w, cc.w);
        s2.x = fmaf(zb, a.x, s2.x); s2.y = fmaf(zb, a.y, s2.y);
        s2.z = fmaf(zb, a.z, s2.z); s2.w = fmaf(zb, a.w, s2.w);
    }
    if (pass < 3) {
        const float i512 = 1.f / 512.f;
        float4 m;
        m.x = 0.5f * (cc.x + s2.x) - (float)(d + 1) * i512 * s2.x;
        m.y = 0.5f * (cc.y + s2.y) - (float)(d + 2) * i512 * s2.y;
        m.z = 0.5f * (cc.z + s2.z) - (float)(d + 3) * i512 * s2.z;
        m.w = 0.5f * (cc.w + s2.w) - (float)(d + 4) * i512 * s2.w;
        *(float4*)(mw + (size_t)pass * SZ + (size_t)bs * DIM + d) = m;
    }
    if (pass > 0)
        *(float4*)(c + (size_t)(pass - 1) * SZ + (size_t)bs * DIM + d) = cc;
}

// ---------------------------------------------------------------------------
union __align__(16) SMem {
    struct { float su[DIM]; float sw[64]; float up[4][DIM]; } hop;
    struct { ushort a[64 * 128]; ushort u[64 * 128]; } log;          // 32 KB
    struct { float red[8]; } r;
};

// Tail: hops (+A3->bf16 convert in parallel), MFMA logits, vocab softmax.
__global__ __launch_bounds__(NTHR, 2)
void k_tail(const float* __restrict__ A,
            const float* __restrict__ T_A,
            const float* __restrict__ mw,
            const float* __restrict__ c,
            const float* __restrict__ u,
            ushort*      __restrict__ ubf,
            ushort*      __restrict__ a3bf,
            float*       __restrict__ pairs,
            float*       __restrict__ out) {
    cg::grid_group grid = cg::this_grid();
    __shared__ SMem sm;
    const int tid = threadIdx.x;
    const int blk = blockIdx.x;

    // ===== Phase 1: hops (blocks 0..63) | A3 -> bf16 (blocks 64..511) =====
    if (blk < BS) {
        const int b    = blk;
        const int wave = tid >> 6;
        const int lane = tid & 63;
        sm.hop.su[tid]       = u[(size_t)b * DIM + tid];
        sm.hop.su[tid + 256] = u[(size_t)b * DIM + tid + 256];
        __syncthreads();
        for (int h = 0; h < NUM_HOP; ++h) {
            const float* mwh = mw + (size_t)h * SZ + (size_t)b * STORY * DIM;
            const float* ch  = c  + (size_t)h * SZ + (size_t)b * STORY * DIM;
            const float4 u0 = *(const float4*)(&sm.hop.su[lane * 8]);
            const float4 u1 = *(const float4*)(&sm.hop.su[lane * 8 + 4]);
            for (int s = wave; s < STORY; s += 4) {
                const float* mrow = mwh + (size_t)s * DIM + lane * 8;
                const float* trow = T_A + (size_t)s * DIM + lane * 8;
                const float4 m0 = *(const float4*)(mrow);
                const float4 m1 = *(const float4*)(mrow + 4);
                const float4 t0 = *(const float4*)(trow);
                const float4 t1 = *(const float4*)(trow + 4);
                float p = (m0.x + t0.x) * u0.x + (m0.y + t0.y) * u0.y +
                          (m0.z + t0.z) * u0.z + (m0.w + t0.w) * u0.w +
                          (m1.x + t1.x) * u1.x + (m1.y + t1.y) * u1.y +
                          (m1.z + t1.z) * u1.z + (m1.w + t1.w) * u1.w;
                for (int off = 32; off; off >>= 1) p += __shfl_down(p, off);
                if (lane == 0) sm.hop.sw[s] = p;
            }
            __syncthreads();
            if (tid < 64) {
                const float v = (tid < STORY) ? sm.hop.sw[tid] : -1e30f;
                float mx = v;
                for (int off = 32; off; off >>= 1) mx = fmaxf(mx, __shfl_down(mx, off));
                mx = __shfl(mx, 0);
                const float e = (tid < STORY) ? __expf(v - mx) : 0.f;
                float smm = e;
                for (int off = 32; off; off >>= 1) smm += __shfl_down(smm, off);
                smm = __shfl(smm, 0);
                if (tid < STORY) sm.hop.sw[tid] = e / smm;
            }
            __syncthreads();
            float4 a0 = make_float4(0.f, 0.f, 0.f, 0.f);
            float4 a1 = make_float4(0.f, 0.f, 0.f, 0.f);
            for (int s = wave; s < STORY; s += 4) {
                const float  w    = sm.hop.sw[s];
                const float* crow = ch + (size_t)s * DIM + lane * 8;
                const float4 c0 = *(const float4*)(crow);
                const float4 c1 = *(const float4*)(crow + 4);
                a0.x = fmaf(w, c0.x, a0.x); a0.y = fmaf(w, c0.y, a0.y);
                a0.z = fmaf(w, c0.z, a0.z); a0.w = fmaf(w, c0.w, a0.w);
                a1.x = fmaf(w, c1.x, a1.x); a1.y = fmaf(w, c1.y, a1.y);
                a1.z = fmaf(w, c1.z, a1.z); a1.w = fmaf(w, c1.w, a1.w);
            }
            *(float4*)(&sm.hop.up[wave][lane * 8])     = a0;
            *(float4*)(&sm.hop.up[wave][lane * 8 + 4]) = a1;
            __syncthreads();
            sm.hop.su[tid] += sm.hop.up[0][tid] + sm.hop.up[1][tid] +
                              sm.hop.up[2][tid] + sm.hop.up[3][tid];
            sm.hop.su[tid + 256] += sm.hop.up[0][tid + 256] + sm.hop.up[1][tid + 256] +
                                    sm.hop.up[2][tid + 256] + sm.hop.up[3][tid + 256];
            __syncthreads();
        }
        ubf[(size_t)b * DIM + tid]       = f2bf(sm.hop.su[tid]);
        ubf[(size_t)b * DIM + tid + 256] = f2bf(sm.hop.su[tid + 256]);
    } else {
        const float* A3 = A + 3 * TBL;              // L3-warm from gather pass 3
        const size_t n8 = TBL / 8;
        for (size_t i = (size_t)(blk - BS) * NTHR + tid; i < n8;
             i += (size_t)(TBLK - BS) * NTHR) {
            const float* src = A3 + i * 8;
            const float4 f0 = *(const float4*)(src);
            const float4 f1 = *(const float4*)(src + 4);
            union { ushort h[8]; uint4 q; } pk;
            pk.h[0] = f2bf(f0.x); pk.h[1] = f2bf(f0.y);
            pk.h[2] = f2bf(f0.z); pk.h[3] = f2bf(f0.w);
            pk.h[4] = f2bf(f1.x); pk.h[5] = f2bf(f1.y);
            pk.h[6] = f2bf(f1.z); pk.h[7] = f2bf(f1.w);
            *(uint4*)(a3bf + i * 8) = pk.q;
        }
    }
    grid.sync();

    // ===== Phase 2: logits = u @ A3^T via bf16 MFMA (blocks 0..499) =====
    if (blk < VOCAB / 64) {
        const int lane = tid & 63;
        const int wave = tid >> 6;
        const int i16  = lane & 15;
        const int quad = lane >> 4;
        const int row0 = blk * 64;
        v4f acc[4];
        #pragma unroll
        for (int nt = 0; nt < 4; ++nt) acc[nt] = (v4f){0.f, 0.f, 0.f, 0.f};
        for (int ko = 0; ko < 4; ++ko) {
            __syncthreads();
            #pragma unroll
            for (int it = 0; it < 4; ++it) {
                const int i = it * 256 + tid;
                const int r = i >> 4, g = i & 15;
                const uint4 v = *(const uint4*)(a3bf + (size_t)(row0 + r) * DIM + ko * 128 + g * 8);
                *(uint4*)(&sm.log.a[r * 128 + ((g ^ (r & 7)) * 8)]) = v;
            }
            #pragma unroll
            for (int it = 0; it < 4; ++it) {
                const int i = it * 256 + tid;
                const int n = i >> 4, g = i & 15;
                const uint4 v = *(const uint4*)(ubf + (size_t)n * DIM + ko * 128 + g * 8);
                *(uint4*)(&sm.log.u[n * 128 + ((g ^ (n & 7)) * 8)]) = v;
            }
            __syncthreads();
            const int arow = wave * 16 + i16;
            #pragma unroll
            for (int ki = 0; ki < 4; ++ki) {
                const int ga = ki * 4 + quad;
                const v8s a = *(const v8s*)(&sm.log.a[arow * 128 + ((ga ^ (arow & 7)) * 8)]);
                #pragma unroll
                for (int nt = 0; nt < 4; ++nt) {
                    const int n = nt * 16 + i16;
                    const v8s bb = *(const v8s*)(&sm.log.u[n * 128 + ((ga ^ (n & 7)) * 8)]);
                    acc[nt] = __builtin_amdgcn_mfma_f32_16x16x32_bf16(a, bb, acc[nt], 0, 0, 0);
                }
            }
        }
        const int vbase = row0 + wave * 16 + quad * 4;
        #pragma unroll
        for (int nt = 0; nt < 4; ++nt) {
            const int bcol = nt * 16 + i16;
            #pragma unroll
            for (int r = 0; r < 4; ++r)
                out[(size_t)bcol * VOCAB + vbase + r] = acc[nt][r];
        }
    }
    grid.sync();

    // ===== Phase 3: vocab softmax partials (b = blk/8, seg = blk%8) =====
    const int vb  = blk >> 3;
    const int seg = blk & 7;
    float* row = out + (size_t)vb * VOCAB + seg * 4000;
    float x[16];
    #pragma unroll
    for (int k = 0; k < 15; ++k) x[k] = row[tid + k * 256];
    const bool extra = (tid < 4000 - 15 * 256);
    x[15] = extra ? row[tid + 15 * 256] : -1e30f;

    float mx = -1e30f;
    #pragma unroll
    for (int k = 0; k < 16; ++k) mx = fmaxf(mx, x[k]);
    for (int off = 32; off; off >>= 1) mx = fmaxf(mx, __shfl_down(mx, off));
    if ((tid & 63) == 0) sm.r.red[tid >> 6] = mx;
    __syncthreads();
    mx = fmaxf(fmaxf(sm.r.red[0], sm.r.red[1]), fmaxf(sm.r.red[2], sm.r.red[3]));
    __syncthreads();
    float sum = 0.f;
    #pragma unroll
    for (int k = 0; k < 16; ++k) { x[k] = __expf(x[k] - mx); sum += x[k]; }
    for (int off = 32; off; off >>= 1) sum += __shfl_down(sum, off);
    if ((tid & 63) == 0) sm.r.red[4 + (tid >> 6)] = sum;
    __syncthreads();
    sum = sm.r.red[4] + sm.r.red[5] + sm.r.red[6] + sm.r.red[7];
    if (tid == 0) { pairs[blk * 2] = mx; pairs[blk * 2 + 1] = sum; }
    grid.sync();

    // ===== Phase 4: combine + normalize (register-cached x[] survive) =====
    float M = -1e30f;
    #pragma unroll
    for (int j = 0; j < 8; ++j) M = fmaxf(M, pairs[(vb * 8 + j) * 2]);
    float S = 0.f;
    #pragma unroll
    for (int j = 0; j < 8; ++j)
        S += pairs[(vb * 8 + j) * 2 + 1] * __expf(pairs[(vb * 8 + j) * 2] - M);
    const float scale = __expf(mx - M) / S;
    #pragma unroll
    for (int k = 0; k < 15; ++k) row[tid + k * 256] = x[k] * scale;
    if (extra) row[tid + 15 * 256] = x[15] * scale;
}

// ---------------------------------------------------------------------------
extern "C" void kernel_launch(void* const* d_in, const int* in_sizes, int n_in,
                              void* d_out, int out_size, void* d_ws, size_t ws_size,
                              hipStream_t stream) {
    const int*   ctx   = (const int*)d_in[0];
    const int*   query = (const int*)d_in[1];
    const float* A     = (const float*)d_in[2];
    const float* T_A   = (const float*)d_in[3];
    float* out = (float*)d_out;

    float*  u     = (float*)d_ws;                         // BS*DIM f
    float*  pairs = u + (size_t)BS * DIM;                 // 1024 f
    ushort* ubf   = (ushort*)(pairs + 1024);              // BS*DIM bf16
    ushort* a3bf  = ubf + (size_t)BS * DIM;               // TBL bf16
    float*  mw    = (float*)(a3bf + TBL);                 // 3*SZ f
    float*  c     = mw + 3 * SZ;                          // 3*SZ f

    k_gather<<<NSENT + BS, 128, 0, stream>>>(A, ctx, query, mw, c, u);

    void* args[] = {(void*)&A, (void*)&T_A, (void*)&mw, (void*)&c, (void*)&u,
                    (void*)&ubf, (void*)&a3bf, (void*)&pairs, (void*)&out};
    hipLaunchCooperativeKernel((void*)k_tail, dim3(TBLK), dim3(NTHR),
                               args, 0, stream);
}